// Round 5
// baseline (274.918 us; speedup 1.0000x reference)
//
#include <hip/hip_runtime.h>
#include <hip/hip_bf16.h>

#define BATCH 16
#define CIN 64
#define COUT 64
#define HH 160
#define WW 160
#define HP 162
#define WP 162

#define ABUF 21760  // shorts per A buffer: 340 pixels * 64 ch (43,520 B)
#define PSTR 161    // prep LDS row stride (floats); odd => conflict-free reads

typedef __attribute__((ext_vector_type(8))) __bf16 bf16x8;
typedef __attribute__((ext_vector_type(4))) float f32x4;
typedef __attribute__((ext_vector_type(8))) unsigned short ushort8;

typedef __attribute__((address_space(1))) const unsigned int gu32;
typedef __attribute__((address_space(3))) unsigned int lu32;

// ---------------------------------------------------------------------------
// Pass 1 (unchanged from R4, harness-verified): x (NCHW fp32) ->
// xs (B,162,162,64) bf16 with shift folded in; weight cvt in trailing blocks.
// ---------------------------------------------------------------------------
__global__ __launch_bounds__(256) void prep(const float* __restrict__ x,
                                            const float* __restrict__ w,
                                            unsigned short* __restrict__ xs,
                                            unsigned short* __restrict__ wb) {
  __shared__ float lds[64 * PSTR];  // 41,216 B

  if (blockIdx.x >= BATCH * HP) {
    int e = (blockIdx.x - BATCH * HP) * 256 + threadIdx.x;
    if (e < 9 * 64 * 64) {
      int tap = e >> 12;
      int o = (e >> 6) & 63;
      int c = e & 63;
      float v = w[((size_t)(o * 64 + c)) * 9 + tap];
      __hip_bfloat16 h = __float2bfloat16(v);
      wb[e] = *reinterpret_cast<unsigned short*>(&h);
    }
    return;
  }

  int y = blockIdx.x % HP;
  int b = blockIdx.x / HP;
  int tid = threadIdx.x;

  // ---- load: global (coalesced along W) -> LDS, plain layout ----
#pragma unroll
  for (int it = 0; it < 10; ++it) {
    int idx = it * 256 + tid;  // 0..2559 = 64 ch x 40 f32x4
    int c = idx / 40;
    int j = idx - c * 40;
    int cm = c % 5;
    int dy = (cm == 2) ? 1 : ((cm == 4) ? -1 : 0);
    int yy = y - dy;  // source row (1..160 valid)
    f32x4 v = {0.f, 0.f, 0.f, 0.f};
    if (yy >= 1 && yy <= HH)
      v = *reinterpret_cast<const f32x4*>(
          x + (((size_t)(b * CIN + c)) * HH + (size_t)(yy - 1)) * WW + j * 4);
    int p0 = c * PSTR + 4 * j;
#pragma unroll
    for (int e = 0; e < 4; ++e) lds[p0 + e] = v[e];
  }
  __syncthreads();

  // ---- store: fixed 8-channel group per thread, 16B stores ----
  int cg = tid & 7;   // channel group: channels cg*8 .. cg*8+7
  int xr = tid >> 3;  // xi = it*32 + xr
  int dxe[8], rowb[8];
#pragma unroll
  for (int e = 0; e < 8; ++e) {
    int c = cg * 8 + e;
    int cm = c % 5;
    dxe[e] = (cm == 1) ? 1 : ((cm == 3) ? -1 : 0);
    rowb[e] = c * PSTR;
  }
  size_t obase = ((size_t)(b * HP + y) * WP) * CIN + cg * 8;
#pragma unroll
  for (int it = 0; it < 6; ++it) {
    int xi = it * 32 + xr;
    if (xi < WP) {
      ushort8 val;
#pragma unroll
      for (int e = 0; e < 8; ++e) {
        int xx = xi - dxe[e] - 1;  // source x (0..159 valid)
        float v = 0.f;
        if (xx >= 0 && xx < WW) v = lds[rowb[e] + xx];
        __hip_bfloat16 h = __float2bfloat16(v);
        val[e] = *reinterpret_cast<unsigned short*>(&h);
      }
      *reinterpret_cast<ushort8*>(xs + obase + (size_t)xi * CIN) = val;
    }
  }
}

// ---------------------------------------------------------------------------
// Pass 2 (v8): PERSISTENT pipelined implicit-GEMM conv, WEIGHTS IN REGISTERS.
//  - 256 blocks (1/CU), 512 threads (8 waves = 2/SIMD), LDS = A dbuf only
//    (2 x 43,520 B = 87 KB; lds_w eliminated).
//  - 8 waves = 4 row-pairs x 2 och-halves. Each wave holds its FULL weight
//    half-set in VGPRs: Breg[18][2] = 144 VGPR, loaded ONCE from global wb
//    (73.7 KB, L2-resident). Inner 18-tap loop reads ONLY A from LDS:
//    per CU per tap 32 ds_read_b128 (was 48 with LDS-B) and the lgkm
//    dependency chain is A-only.
//  - acc[4][2]=32 + Breg 144 + Ab 32 ~= 230 VGPR; __launch_bounds__(512,2).
//  - Stage of tile t+1 issued before compute(t); single barrier per tile
//    (drains stage where the data is needed); epilogue stores after the
//    barrier overlap the next tile's stage+compute.
//  - A chunk-XOR swizzle unchanged (0 conflicts measured in R1/R3).
// MFMA mapping unchanged (harness-verified): D[row=q*4+reg][col=l15];
// x = x0 + mt*16 + q*4 + reg, o = nh*32 + ns*16 + l15, row = y0 + 2*rp + rr.
// ---------------------------------------------------------------------------
__global__ __launch_bounds__(512, 2) void conv_mfma(const unsigned short* __restrict__ xs,
                                                    const unsigned short* __restrict__ wb,
                                                    float* __restrict__ out) {
  __shared__ __align__(16) unsigned short lds_a[ABUF];  // 43,520 B
  __shared__ __align__(16) unsigned short lds_b[ABUF];  // 43,520 B

  int tid = threadIdx.x;
  int blk = blockIdx.x;
  int tile0 = (blk & 7) * 32 + (blk >> 3);  // XCD-chunked, bijective (256%8==0)
  int ntiles = (tile0 < 64) ? 7 : 6;        // 64*7 + 192*6 = 1600

  int wv = tid >> 6;   // 0..7
  int rp = wv >> 1;    // row-pair 0..3
  int nh = wv & 1;     // och half 0..1
  int lane = tid & 63;
  int l15 = lane & 15;
  int q = lane >> 4;

  // tile-invariant per-thread A-staging source offsets (shorts)
  int goff[6];
#pragma unroll
  for (int r = 0; r < 6; ++r) {
    int u = r * 512 + tid;          // chunk index 0..3071 (valid < 2720)
    int p = u >> 3;                 // pixel
    int j = (u & 7) ^ (p & 7);      // source chunk (inverse swizzle)
    int pr = p / 34, pc = p - pr * 34;
    goff[r] = (pr * WP + pc) * CIN + j * 8;
  }

#define STAGE_TO(BUFARR, T_)                                                   \
  {                                                                            \
    int sb_ = (T_) / 100;                                                      \
    int srr_ = (T_) - sb_ * 100;                                               \
    int sti_ = srr_ / 5, stj_ = srr_ - sti_ * 5;                               \
    const unsigned short* srcb_ = xs +                                         \
        ((size_t)sb_ * HP + (size_t)(sti_ * 8)) * WP * CIN +                   \
        (size_t)(stj_ * 32) * CIN;                                             \
    unsigned short* dst0_ = (BUFARR) + wv * 512;                               \
    _Pragma("unroll") for (int r = 0; r < 5; ++r)                              \
        __builtin_amdgcn_global_load_lds((gu32*)(srcb_ + goff[r]),             \
                                         (lu32*)(dst0_ + r * 4096), 16, 0, 0); \
    if (tid < 160)                                                             \
      __builtin_amdgcn_global_load_lds((gu32*)(srcb_ + goff[5]),               \
                                       (lu32*)(dst0_ + 5 * 4096), 16, 0, 0);   \
  }

#define LOAD_A(RBUF, bufp, tt)                                                 \
  {                                                                            \
    const int ch_ = (tt) / 9, ky_ = ((tt) % 9) / 3, kx_ = (tt) % 3;            \
    _Pragma("unroll") for (int rr = 0; rr < 2; ++rr)                           \
      _Pragma("unroll") for (int mt = 0; mt < 2; ++mt) {                       \
        int pix = (2 * rp + rr + ky_) * 34 + kx_ + l15 + mt * 16;              \
        int chunk = (ch_ * 4 + q) ^ (pix & 7);                                 \
        Ab[bufp][rr * 2 + mt] =                                                \
            *reinterpret_cast<const bf16x8*>(&(RBUF)[pix * 64 + chunk * 8]);   \
      }                                                                        \
  }

#define TILE_BODY(I_, RBUF, WBUF)                                              \
  {                                                                            \
    int t_ = tile0 + 256 * (I_);                                               \
    int b_ = t_ / 100;                                                         \
    int rr_ = t_ - b_ * 100;                                                   \
    int ti_ = rr_ / 5, tj_ = rr_ - ti_ * 5;                                    \
    int y0_ = ti_ * 8, x0_ = tj_ * 32;                                         \
    if ((I_) + 1 < ntiles) STAGE_TO(WBUF, tile0 + 256 * ((I_) + 1));           \
    _Pragma("unroll") for (int a_ = 0; a_ < 4; ++a_)                           \
      _Pragma("unroll") for (int c2_ = 0; c2_ < 2; ++c2_)                      \
        acc[a_][c2_] = (f32x4){0.f, 0.f, 0.f, 0.f};                            \
    LOAD_A(RBUF, 0, 0);                                                        \
    _Pragma("unroll") for (int tt = 0; tt < 18; ++tt) {                        \
      if (tt + 1 < 18) LOAD_A(RBUF, (tt + 1) & 1, tt + 1);                     \
      __builtin_amdgcn_s_setprio(1);                                           \
      _Pragma("unroll") for (int am = 0; am < 4; ++am)                         \
        _Pragma("unroll") for (int ns = 0; ns < 2; ++ns)                       \
          acc[am][ns] = __builtin_amdgcn_mfma_f32_16x16x32_bf16(               \
              Ab[tt & 1][am], Breg[tt][ns], acc[am][ns], 0, 0, 0);             \
      __builtin_amdgcn_s_setprio(0);                                           \
    }                                                                          \
    __syncthreads();                                                           \
    _Pragma("unroll") for (int rr2 = 0; rr2 < 2; ++rr2)                        \
      _Pragma("unroll") for (int mt = 0; mt < 2; ++mt) {                       \
        int orow_ = y0_ + 2 * rp + rr2;                                        \
        int xo_ = x0_ + mt * 16 + q * 4;                                       \
        _Pragma("unroll") for (int ns = 0; ns < 2; ++ns) {                     \
          int o_ = nh * 32 + ns * 16 + l15;                                    \
          *reinterpret_cast<f32x4*>(                                           \
              out + ((size_t)(b_ * COUT + o_) * HH + (size_t)orow_) * WW +     \
              xo_) = acc[rr2 * 2 + mt][ns];                                    \
        }                                                                      \
      }                                                                        \
  }

  f32x4 acc[4][2];
  bf16x8 Ab[2][4];
  bf16x8 Breg[18][2];

  // ---- prologue: stage tile0 + load this wave's weight half into VGPRs ----
  STAGE_TO(lds_a, tile0);
#pragma unroll
  for (int tt = 0; tt < 18; ++tt) {
    const int ch_ = tt / 9, tap_ = tt % 9;
#pragma unroll
    for (int ns = 0; ns < 2; ++ns)
      Breg[tt][ns] = *reinterpret_cast<const bf16x8*>(
          wb + tap_ * 4096 + (nh * 2 + ns) * 1024 + l15 * 64 + ch_ * 32 + q * 8);
  }
  __syncthreads();

  for (int i = 0; i < ntiles; i += 2) {
    TILE_BODY(i, lds_a, lds_b);
    if (i + 1 < ntiles) TILE_BODY(i + 1, lds_b, lds_a);
  }

#undef TILE_BODY
#undef LOAD_A
#undef STAGE_TO
}

extern "C" void kernel_launch(void* const* d_in, const int* in_sizes, int n_in,
                              void* d_out, int out_size, void* d_ws, size_t ws_size,
                              hipStream_t stream) {
  const float* x = (const float*)d_in[0];
  const float* w = (const float*)d_in[1];
  float* out = (float*)d_out;

  unsigned short* xs = (unsigned short*)d_ws;  // 16*162*162*64 bf16 = 53.7 MB
  unsigned short* wb = (unsigned short*)((char*)d_ws + (size_t)BATCH * HP * WP * CIN * 2);

  hipLaunchKernelGGL(prep, dim3(BATCH * HP + 144), dim3(256), 0, stream, x, w, xs, wb);
  hipLaunchKernelGGL(conv_mfma, dim3(256), dim3(512), 0, stream, xs, wb, out);
}

// Round 6
// 226.243 us; speedup vs baseline: 1.2151x; 1.2151x over previous
//
#include <hip/hip_runtime.h>
#include <hip/hip_bf16.h>

#define BATCH 16
#define CIN 64
#define COUT 64
#define HH 160
#define WW 160
#define HP 162
#define WP 162

#define ABUF 21760  // shorts per A buffer: 340 pixels * 64 ch (43,520 B)
#define PSTR 161    // prep LDS row stride (floats); odd => conflict-free reads

typedef __attribute__((ext_vector_type(8))) __bf16 bf16x8;
typedef __attribute__((ext_vector_type(4))) float f32x4;
typedef __attribute__((ext_vector_type(8))) unsigned short ushort8;

typedef __attribute__((address_space(1))) const unsigned int gu32;
typedef __attribute__((address_space(3))) unsigned int lu32;

// ---------------------------------------------------------------------------
// Pass 1 (unchanged, harness-verified): x (NCHW fp32) -> xs (B,162,162,64)
// bf16 with shift folded in; weight cvt in trailing blocks.
// ---------------------------------------------------------------------------
__global__ __launch_bounds__(256) void prep(const float* __restrict__ x,
                                            const float* __restrict__ w,
                                            unsigned short* __restrict__ xs,
                                            unsigned short* __restrict__ wb) {
  __shared__ float lds[64 * PSTR];  // 41,216 B

  if (blockIdx.x >= BATCH * HP) {
    int e = (blockIdx.x - BATCH * HP) * 256 + threadIdx.x;
    if (e < 9 * 64 * 64) {
      int tap = e >> 12;
      int o = (e >> 6) & 63;
      int c = e & 63;
      float v = w[((size_t)(o * 64 + c)) * 9 + tap];
      __hip_bfloat16 h = __float2bfloat16(v);
      wb[e] = *reinterpret_cast<unsigned short*>(&h);
    }
    return;
  }

  int y = blockIdx.x % HP;
  int b = blockIdx.x / HP;
  int tid = threadIdx.x;

  // ---- load: global (coalesced along W) -> LDS, plain layout ----
#pragma unroll
  for (int it = 0; it < 10; ++it) {
    int idx = it * 256 + tid;  // 0..2559 = 64 ch x 40 f32x4
    int c = idx / 40;
    int j = idx - c * 40;
    int cm = c % 5;
    int dy = (cm == 2) ? 1 : ((cm == 4) ? -1 : 0);
    int yy = y - dy;  // source row (1..160 valid)
    f32x4 v = {0.f, 0.f, 0.f, 0.f};
    if (yy >= 1 && yy <= HH)
      v = *reinterpret_cast<const f32x4*>(
          x + (((size_t)(b * CIN + c)) * HH + (size_t)(yy - 1)) * WW + j * 4);
    int p0 = c * PSTR + 4 * j;
#pragma unroll
    for (int e = 0; e < 4; ++e) lds[p0 + e] = v[e];
  }
  __syncthreads();

  // ---- store: fixed 8-channel group per thread, 16B stores ----
  int cg = tid & 7;   // channel group: channels cg*8 .. cg*8+7
  int xr = tid >> 3;  // xi = it*32 + xr
  int dxe[8], rowb[8];
#pragma unroll
  for (int e = 0; e < 8; ++e) {
    int c = cg * 8 + e;
    int cm = c % 5;
    dxe[e] = (cm == 1) ? 1 : ((cm == 3) ? -1 : 0);
    rowb[e] = c * PSTR;
  }
  size_t obase = ((size_t)(b * HP + y) * WP) * CIN + cg * 8;
#pragma unroll
  for (int it = 0; it < 6; ++it) {
    int xi = it * 32 + xr;
    if (xi < WP) {
      ushort8 val;
#pragma unroll
      for (int e = 0; e < 8; ++e) {
        int xx = xi - dxe[e] - 1;  // source x (0..159 valid)
        float v = 0.f;
        if (xx >= 0 && xx < WW) v = lds[rowb[e] + xx];
        __hip_bfloat16 h = __float2bfloat16(v);
        val[e] = *reinterpret_cast<unsigned short*>(&h);
      }
      *reinterpret_cast<ushort8*>(xs + obase + (size_t)xi * CIN) = val;
    }
  }
}

// ---------------------------------------------------------------------------
// Pass 2 (v9): PERSISTENT pipelined implicit-GEMM conv, weights in LDS,
// 1024 threads = 16 waves = 4 waves/SIMD (max TLP at 1 block/CU).
//  - R5 lesson: weights-in-VGPR is rematerialized by the compiler (VGPR
//    capped at 128, FETCH +43MB) -> weights stay in LDS (R3 structure,
//    FETCH 27.6MB, zero-VMEM inner loop).
//  - LDS: A dbuf 2x43,520 + W 73,728 = 160,768 B -> exactly 1 block/CU.
//  - 16 waves = 8 rows x 2 och-halves; per wave acc[2][2] (16 VGPR),
//    4 ds_read + 4 MFMA per tap. Every wave's lgkm stall covered by the
//    3 co-resident waves on its SIMD.
//  - Stage of tile t+1 issued before compute(t); ONE barrier per tile
//    (vmcnt drain where data is needed); epilogue stores after barrier.
//  - Chunk-XOR swizzles on A, B, and stage source unchanged (0 conflicts
//    measured R1/R3).
// MFMA mapping unchanged (harness-verified): D[row=q*4+reg][col=l15];
// x = x0 + mt*16 + q*4 + reg, o = nh*32 + ns*16 + l15, row = y0 + (wv>>1).
// ---------------------------------------------------------------------------
__global__ __launch_bounds__(1024, 4) void conv_mfma(const unsigned short* __restrict__ xs,
                                                     const unsigned short* __restrict__ wb,
                                                     float* __restrict__ out) {
  __shared__ __align__(16) unsigned short lds_a[ABUF];         // 43,520 B
  __shared__ __align__(16) unsigned short lds_b[ABUF];         // 43,520 B
  __shared__ __align__(16) unsigned short lds_w[9 * 64 * 64];  // 73,728 B

  int tid = threadIdx.x;
  int blk = blockIdx.x;
  int tile0 = (blk & 7) * 32 + (blk >> 3);  // XCD-chunked, bijective (256%8==0)
  int ntiles = (tile0 < 64) ? 7 : 6;        // 64*7 + 192*6 = 1600

  int wv = tid >> 6;   // 0..15
  int rw = wv >> 1;    // output row within tile 0..7
  int nh = wv & 1;     // och half
  int lane = tid & 63;
  int l15 = lane & 15;
  int q = lane >> 4;

  // tile-invariant per-thread A-staging source offsets (shorts)
  int goff[3];
#pragma unroll
  for (int r = 0; r < 3; ++r) {
    int u = r * 1024 + tid;         // chunk index (valid < 2720)
    int p = u >> 3;                 // pixel
    int j = (u & 7) ^ (p & 7);      // source chunk (inverse swizzle)
    int pr = p / 34, pc = p - pr * 34;
    goff[r] = (pr * WP + pc) * CIN + j * 8;
  }

  // per-lane B bases in lds_w (shorts): chunk' = (ch*4+q) ^ (l15&7)
  int bw0 = l15 * 64 + ((q ^ (l15 & 7)) * 8);        // ch = 0
  int bw1 = l15 * 64 + (((4 + q) ^ (l15 & 7)) * 8);  // ch = 1

#define STAGE_TO(BUFARR, T_)                                                   \
  {                                                                            \
    int sb_ = (T_) / 100;                                                      \
    int srr_ = (T_) - sb_ * 100;                                               \
    int sti_ = srr_ / 5, stj_ = srr_ - sti_ * 5;                               \
    const unsigned short* srcb_ = xs +                                         \
        ((size_t)sb_ * HP + (size_t)(sti_ * 8)) * WP * CIN +                   \
        (size_t)(stj_ * 32) * CIN;                                             \
    _Pragma("unroll") for (int r = 0; r < 3; ++r) {                            \
      int u_ = r * 1024 + tid;                                                 \
      if (u_ < 2720)                                                           \
        __builtin_amdgcn_global_load_lds((gu32*)(srcb_ + goff[r]),             \
                                         (lu32*)((BUFARR) + (u_ & ~63) * 8),   \
                                         16, 0, 0);                            \
    }                                                                          \
  }

#define LOAD_A(RBUF, bufp, tt)                                                 \
  {                                                                            \
    const int ch_ = (tt) / 9, ky_ = ((tt) % 9) / 3, kx_ = (tt) % 3;            \
    _Pragma("unroll") for (int mt = 0; mt < 2; ++mt) {                         \
      int pix = (rw + ky_) * 34 + kx_ + l15 + mt * 16;                         \
      int chunk = (ch_ * 4 + q) ^ (pix & 7);                                   \
      Ab[bufp][mt] =                                                           \
          *reinterpret_cast<const bf16x8*>(&(RBUF)[pix * 64 + chunk * 8]);     \
    }                                                                          \
  }

#define LOAD_BW(bufp, tt)                                                      \
  {                                                                            \
    const int ch_ = (tt) / 9, tap_ = (tt) % 9;                                 \
    _Pragma("unroll") for (int ns = 0; ns < 2; ++ns)                           \
        Bb[bufp][ns] = *reinterpret_cast<const bf16x8*>(                       \
            &lds_w[tap_ * 4096 + (nh * 2 + ns) * 1024 + (ch_ ? bw1 : bw0)]);   \
  }

#define TILE_BODY(I_, RBUF, WBUF)                                              \
  {                                                                            \
    int t_ = tile0 + 256 * (I_);                                               \
    int b_ = t_ / 100;                                                         \
    int rr_ = t_ - b_ * 100;                                                   \
    int ti_ = rr_ / 5, tj_ = rr_ - ti_ * 5;                                    \
    int y0_ = ti_ * 8, x0_ = tj_ * 32;                                         \
    if ((I_) + 1 < ntiles) STAGE_TO(WBUF, tile0 + 256 * ((I_) + 1));           \
    _Pragma("unroll") for (int a_ = 0; a_ < 2; ++a_)                           \
      _Pragma("unroll") for (int c2_ = 0; c2_ < 2; ++c2_)                      \
        acc[a_][c2_] = (f32x4){0.f, 0.f, 0.f, 0.f};                            \
    LOAD_A(RBUF, 0, 0);                                                        \
    LOAD_BW(0, 0);                                                             \
    _Pragma("unroll") for (int tt = 0; tt < 18; ++tt) {                        \
      if (tt + 1 < 18) {                                                       \
        LOAD_A(RBUF, (tt + 1) & 1, tt + 1);                                    \
        LOAD_BW((tt + 1) & 1, tt + 1);                                         \
      }                                                                        \
      __builtin_amdgcn_s_setprio(1);                                           \
      _Pragma("unroll") for (int mt = 0; mt < 2; ++mt)                         \
        _Pragma("unroll") for (int ns = 0; ns < 2; ++ns)                       \
          acc[mt][ns] = __builtin_amdgcn_mfma_f32_16x16x32_bf16(               \
              Ab[tt & 1][mt], Bb[tt & 1][ns], acc[mt][ns], 0, 0, 0);           \
      __builtin_amdgcn_s_setprio(0);                                           \
    }                                                                          \
    __syncthreads();                                                           \
    _Pragma("unroll") for (int mt = 0; mt < 2; ++mt) {                         \
      int orow_ = y0_ + rw;                                                    \
      int xo_ = x0_ + mt * 16 + q * 4;                                         \
      _Pragma("unroll") for (int ns = 0; ns < 2; ++ns) {                       \
        int o_ = nh * 32 + ns * 16 + l15;                                      \
        *reinterpret_cast<f32x4*>(                                             \
            out + ((size_t)(b_ * COUT + o_) * HH + (size_t)orow_) * WW + xo_) = \
            acc[mt][ns];                                                       \
      }                                                                        \
    }                                                                          \
  }

  f32x4 acc[2][2];
  bf16x8 Ab[2][2];
  bf16x8 Bb[2][2];

  // ---- prologue: stage weights (once) + tile0, one barrier ----
  // weights: 4608 chunks; lds chunk u holds global chunk (u&7)^(orow&7)
  // of o-row orow=u>>3 (the read-side involution).
#pragma unroll
  for (int r = 0; r < 5; ++r) {
    int u = r * 1024 + tid;
    if (u < 4608) {
      int orow = u >> 3;
      int jj = (u & 7) ^ (orow & 7);
      __builtin_amdgcn_global_load_lds((gu32*)(wb + orow * 64 + jj * 8),
                                       (lu32*)(lds_w + (u & ~63) * 8), 16, 0, 0);
    }
  }
  STAGE_TO(lds_a, tile0);
  __syncthreads();

  for (int i = 0; i < ntiles; i += 2) {
    TILE_BODY(i, lds_a, lds_b);
    if (i + 1 < ntiles) TILE_BODY(i + 1, lds_b, lds_a);
  }

#undef TILE_BODY
#undef LOAD_BW
#undef LOAD_A
#undef STAGE_TO
}

extern "C" void kernel_launch(void* const* d_in, const int* in_sizes, int n_in,
                              void* d_out, int out_size, void* d_ws, size_t ws_size,
                              hipStream_t stream) {
  const float* x = (const float*)d_in[0];
  const float* w = (const float*)d_in[1];
  float* out = (float*)d_out;

  unsigned short* xs = (unsigned short*)d_ws;  // 16*162*162*64 bf16 = 53.7 MB
  unsigned short* wb = (unsigned short*)((char*)d_ws + (size_t)BATCH * HP * WP * CIN * 2);

  hipLaunchKernelGGL(prep, dim3(BATCH * HP + 144), dim3(256), 0, stream, x, w, xs, wb);
  hipLaunchKernelGGL(conv_mfma, dim3(256), dim3(1024), 0, stream, xs, wb, out);
}